// Round 3
// baseline (4190.734 us; speedup 1.0000x reference)
//
#include <hip/hip_runtime.h>
#include <math.h>

#define NROWS   32768
#define EDIM    512
#define NE      1024
#define NLAYERS 4

// ---- ws offsets (bytes) ----
#define OFF_LOSS   0          // 4 doubles
#define OFF_COUNTS 32         // 4096 ints
#define OFF_A      16416      // 32768 floats (row sums-of-squares, f32 numpy-pairwise)
#define OFF_B      147488     // 4096 floats (codebook sums-of-squares)
#define OFF_IDX    163872     // 4*32768 ints
#define OFF_RES    1048576    // 16777216 floats (64 MB residual)

// ---------------------------------------------------------------------------
// numpy-pairwise f32 sum of squares per row (n=512).
// Structure: 4 base-blocks of 128; base = 8 accumulator chains (16 sequential
// adds each) + tree ((r0+r1)+(r2+r3))+((r4+r5)+(r6+r7)); top = (B0+B1)+(B2+B3).
// Wave per row; lanes 0..31 run the 32 chains; shfl-xor butterfly = exact tree
// (f32 add is bitwise commutative).
__global__ __launch_bounds__(256) void pairsum_kernel(const float* __restrict__ src,
                                                      float* __restrict__ dst) {
    __shared__ float buf[4][EDIM];
    const int tid = threadIdx.x, lane = tid & 63, w = tid >> 6;
    const int row = blockIdx.x * 4 + w;
    const float4* s4 = reinterpret_cast<const float4*>(src + (size_t)row * EDIM);
    float4 a = s4[lane * 2], b = s4[lane * 2 + 1];
    float* br = buf[w];
    br[lane*8+0]=a.x; br[lane*8+1]=a.y; br[lane*8+2]=a.z; br[lane*8+3]=a.w;
    br[lane*8+4]=b.x; br[lane*8+5]=b.y; br[lane*8+6]=b.z; br[lane*8+7]=b.w;
    __syncthreads();
    if (lane < 32) {
        const int bb = lane >> 3, j = lane & 7;
        const float* p = &br[128 * bb + j];
        float v = p[0];
        float r = __fmul_rn(v, v);
        #pragma unroll
        for (int i = 1; i < 16; ++i) { v = p[8 * i]; r = __fadd_rn(r, __fmul_rn(v, v)); }
        r = __fadd_rn(r, __shfl_xor(r, 1));
        r = __fadd_rn(r, __shfl_xor(r, 2));
        r = __fadd_rn(r, __shfl_xor(r, 4));
        r = __fadd_rn(r, __shfl_xor(r, 8));
        r = __fadd_rn(r, __shfl_xor(r, 16));
        if (lane == 0) dst[row] = r;
    }
}

// ---------------------------------------------------------------------------
// f32-faithful argmin for one layer.
// Block = 512 threads (8 waves), 32 rows/block (4 rows per wave).
// Codebook in 16 tiles of 64 codes; each tile in 2 k-halves of 256 staged to
// LDS code-major with per-row rotation (bank-optimal b128). Lane = code.
// Chain: s = fmaf((2z)_k, c_k, s), k ascending 0..511 (replicates sgemm).
// d = f32((A + B_code) - s); strict < scan => np.argmin first-index ties.
__global__ __launch_bounds__(512) void argmin_kernel(const float* __restrict__ resin,
                                                     const float* __restrict__ cbl,
                                                     const float* __restrict__ Arow,
                                                     const float* __restrict__ Bcb,
                                                     int* __restrict__ idxout) {
    __shared__ float z2[32][EDIM];      // 64 KB, doubled residual rows
    __shared__ float cbT[64 * 256];     // 64 KB, one k-half, rotated code-major
    const int tid = threadIdx.x, lane = tid & 63, w = tid >> 6;
    const int row0 = blockIdx.x * 32;

    // stage z2 = 2*residual (exact f32 doubling), 32 rows x 512
    {
        const int r = tid >> 4;              // 0..31
        const int c0 = (tid & 15) * 32;      // 0..480
        const float4* s4 = reinterpret_cast<const float4*>(resin + (size_t)(row0 + r) * EDIM + c0);
        #pragma unroll
        for (int q = 0; q < 8; ++q) {
            float4 v = s4[q];
            z2[r][c0 + q*4 + 0] = 2.0f * v.x;
            z2[r][c0 + q*4 + 1] = 2.0f * v.y;
            z2[r][c0 + q*4 + 2] = 2.0f * v.z;
            z2[r][c0 + q*4 + 3] = 2.0f * v.w;
        }
    }

    float Av0 = Arow[row0 + w*4 + 0];
    float Av1 = Arow[row0 + w*4 + 1];
    float Av2 = Arow[row0 + w*4 + 2];
    float Av3 = Arow[row0 + w*4 + 3];

    float best0 = INFINITY, best1 = INFINITY, best2 = INFINITY, best3 = INFINITY;
    int bi0 = 0, bi1 = 0, bi2 = 0, bi3 = 0;

    for (int tile = 0; tile < 16; ++tile) {
        float s0 = 0.0f, s1 = 0.0f, s2 = 0.0f, s3 = 0.0f;
        for (int kh = 0; kh < 2; ++kh) {
            __syncthreads();   // previous half fully consumed (also covers z2 staging)
            // stage cbT: 64 codes x 256 k, physical col = (k + 4*code) & 255
            {
                const int cl = tid >> 3;            // 0..63
                const int kq = (tid & 7) * 4;       // 0,4,..,28
                const float* gsrc = cbl + (size_t)(tile*64 + cl) * EDIM + kh*256;
                #pragma unroll
                for (int pass = 0; pass < 8; ++pass) {
                    const int k = pass * 32 + kq;
                    float4 v = *reinterpret_cast<const float4*>(gsrc + k);
                    *reinterpret_cast<float4*>(&cbT[cl*256 + ((k + 4*cl) & 255)]) = v;
                }
            }
            __syncthreads();
            const float* zr0 = &z2[w*4 + 0][kh*256];
            const float* zr1 = &z2[w*4 + 1][kh*256];
            const float* zr2 = &z2[w*4 + 2][kh*256];
            const float* zr3 = &z2[w*4 + 3][kh*256];
            const float* crow = &cbT[lane * 256];
            #pragma unroll 8
            for (int k = 0; k < 256; k += 4) {
                float4 cv = *reinterpret_cast<const float4*>(&crow[(k + 4*lane) & 255]);
                float4 za = *reinterpret_cast<const float4*>(zr0 + k);
                float4 zb = *reinterpret_cast<const float4*>(zr1 + k);
                float4 zc = *reinterpret_cast<const float4*>(zr2 + k);
                float4 zd = *reinterpret_cast<const float4*>(zr3 + k);
                s0 = fmaf(za.x, cv.x, s0); s0 = fmaf(za.y, cv.y, s0);
                s0 = fmaf(za.z, cv.z, s0); s0 = fmaf(za.w, cv.w, s0);
                s1 = fmaf(zb.x, cv.x, s1); s1 = fmaf(zb.y, cv.y, s1);
                s1 = fmaf(zb.z, cv.z, s1); s1 = fmaf(zb.w, cv.w, s1);
                s2 = fmaf(zc.x, cv.x, s2); s2 = fmaf(zc.y, cv.y, s2);
                s2 = fmaf(zc.z, cv.z, s2); s2 = fmaf(zc.w, cv.w, s2);
                s3 = fmaf(zd.x, cv.x, s3); s3 = fmaf(zd.y, cv.y, s3);
                s3 = fmaf(zd.z, cv.z, s3); s3 = fmaf(zd.w, cv.w, s3);
            }
        }
        const int code = tile * 64 + lane;
        const float Bv = Bcb[code];
        float d;
        d = __fsub_rn(__fadd_rn(Av0, Bv), s0); if (d < best0) { best0 = d; bi0 = code; }
        d = __fsub_rn(__fadd_rn(Av1, Bv), s1); if (d < best1) { best1 = d; bi1 = code; }
        d = __fsub_rn(__fadd_rn(Av2, Bv), s2); if (d < best2) { best2 = d; bi2 = code; }
        d = __fsub_rn(__fadd_rn(Av3, Bv), s3); if (d < best3) { best3 = d; bi3 = code; }
    }

    // per-row 64-lane butterfly argmin, ties -> lowest code (np.argmin)
    for (int off = 32; off > 0; off >>= 1) {
        float ov; int oi;
        ov = __shfl_xor(best0, off); oi = __shfl_xor(bi0, off);
        if (ov < best0 || (ov == best0 && oi < bi0)) { best0 = ov; bi0 = oi; }
        ov = __shfl_xor(best1, off); oi = __shfl_xor(bi1, off);
        if (ov < best1 || (ov == best1 && oi < bi1)) { best1 = ov; bi1 = oi; }
        ov = __shfl_xor(best2, off); oi = __shfl_xor(bi2, off);
        if (ov < best2 || (ov == best2 && oi < bi2)) { best2 = ov; bi2 = oi; }
        ov = __shfl_xor(best3, off); oi = __shfl_xor(bi3, off);
        if (ov < best3 || (ov == best3 && oi < bi3)) { best3 = ov; bi3 = oi; }
    }
    if (lane == 0) {
        idxout[row0 + w*4 + 0] = bi0;
        idxout[row0 + w*4 + 1] = bi1;
        idxout[row0 + w*4 + 2] = bi2;
        idxout[row0 + w*4 + 3] = bi3;
    }
}

// ---------------------------------------------------------------------------
// Residual update + loss SSE + histogram + index-as-float write.
__global__ __launch_bounds__(256) void update_kernel(const float* resin, float* resout,
                                                     const float* __restrict__ cb,
                                                     const int* __restrict__ idx,
                                                     double* __restrict__ lossacc,
                                                     int* __restrict__ counts,
                                                     float* __restrict__ idxf) {
    int tid  = threadIdx.x;
    int lane = tid & 63;
    int waveg = blockIdx.x * 4 + (tid >> 6);   // 0..1023
    double lpart = 0.0;
    for (int row = waveg; row < NROWS; row += 1024) {
        int code = idx[row];
        const float4* rin  = reinterpret_cast<const float4*>(resin + (size_t)row * EDIM);
        const float4* cin  = reinterpret_cast<const float4*>(cb + (size_t)code * EDIM);
        float4*       rout = reinterpret_cast<float4*>(resout + (size_t)row * EDIM);
        #pragma unroll
        for (int j = 0; j < 2; ++j) {
            float4 r = rin[lane + 64 * j];
            float4 c = cin[lane + 64 * j];
            float4 o = make_float4(r.x - c.x, r.y - c.y, r.z - c.z, r.w - c.w);
            rout[lane + 64 * j] = o;
            lpart += (double)o.x * o.x + (double)o.y * o.y
                   + (double)o.z * o.z + (double)o.w * o.w;
        }
        if (lane == 0) {
            atomicAdd(&counts[code], 1);
            idxf[row] = (float)code;
        }
    }
    __shared__ double red[256];
    red[tid] = lpart;
    __syncthreads();
    for (int s = 128; s > 0; s >>= 1) {
        if (tid < s) red[tid] += red[tid + s];
        __syncthreads();
    }
    if (tid == 0) atomicAdd(lossacc, red[0]);
}

// ---------------------------------------------------------------------------
// z_q_sum = z - residual_final, stores to the 4B-offset output region.
__global__ __launch_bounds__(256) void zqsum_kernel(const float* __restrict__ z,
                                                    const float* __restrict__ res,
                                                    float* __restrict__ outz) {
    size_t i4 = (size_t)blockIdx.x * 256 + threadIdx.x;
    const float4* z4 = reinterpret_cast<const float4*>(z);
    const float4* r4 = reinterpret_cast<const float4*>(res);
    float4 zv = z4[i4];
    float4 rv = r4[i4];
    size_t b = i4 * 4;
    outz[b + 0] = zv.x - rv.x;
    outz[b + 1] = zv.y - rv.y;
    outz[b + 2] = zv.z - rv.z;
    outz[b + 3] = zv.w - rv.w;
}

// ---------------------------------------------------------------------------
__global__ __launch_bounds__(256) void finalize_kernel(const double* __restrict__ lossacc,
                                                       const int* __restrict__ counts,
                                                       float* __restrict__ out_loss,
                                                       float* __restrict__ out_perp) {
    __shared__ double red[256];
    int tid = threadIdx.x;
    if (tid == 0) {
        double t = 0.25 * (lossacc[0] + lossacc[1] + lossacc[2] + lossacc[3]) / 16777216.0;
        out_loss[0] = (float)t;
    }
    for (int l = 0; l < NLAYERS; ++l) {
        double s = 0.0;
        for (int c = tid; c < NE; c += 256) {
            double p = counts[l * NE + c] * (1.0 / 32768.0);
            s += p * log(p + 1e-10);
        }
        red[tid] = s;
        __syncthreads();
        for (int st = 128; st > 0; st >>= 1) {
            if (tid < st) red[tid] += red[tid + st];
            __syncthreads();
        }
        if (tid == 0) out_perp[l] = (float)exp(-red[0]);
        __syncthreads();
    }
}

// ---------------------------------------------------------------------------
extern "C" void kernel_launch(void* const* d_in, const int* in_sizes, int n_in,
                              void* d_out, int out_size, void* d_ws, size_t ws_size,
                              hipStream_t stream) {
    const float* z  = (const float*)d_in[0];
    const float* cb = (const float*)d_in[1];
    float* out  = (float*)d_out;
    float* outz = out + 1;
    float* idxf = out + 1 + 16777216;
    float* perp = out + 1 + 16777216 + 131072;

    char* ws = (char*)d_ws;
    double* lossacc = (double*)(ws + OFF_LOSS);
    int*    counts  = (int*)(ws + OFF_COUNTS);
    float*  Aws     = (float*)(ws + OFF_A);
    float*  Bws     = (float*)(ws + OFF_B);
    int*    idxbuf  = (int*)(ws + OFF_IDX);
    float*  res     = (float*)(ws + OFF_RES);

    hipMemsetAsync(ws, 0, 32 + 4096 * 4, stream);              // loss + counts
    pairsum_kernel<<<1024, 256, 0, stream>>>(cb, Bws);         // 4096 codebook rows

    for (int l = 0; l < NLAYERS; ++l) {
        const float* rin = (l == 0) ? z : res;
        pairsum_kernel<<<8192, 256, 0, stream>>>(rin, Aws);    // 32768 residual rows
        argmin_kernel<<<1024, 512, 0, stream>>>(rin,
                                                cb + (size_t)l * NE * EDIM,
                                                Aws,
                                                Bws + l * NE,
                                                idxbuf + l * NROWS);
        update_kernel<<<256, 256, 0, stream>>>(rin, res,
                                               cb + (size_t)l * NE * EDIM,
                                               idxbuf + l * NROWS,
                                               lossacc + l,
                                               counts + l * NE,
                                               idxf + l * NROWS);
    }
    zqsum_kernel<<<16384, 256, 0, stream>>>(z, res, outz);
    finalize_kernel<<<1, 256, 0, stream>>>(lossacc, counts, out, perp);
}